// Round 8
// baseline (24486.818 us; speedup 1.0000x reference)
//
#include <hip/hip_runtime.h>
#include <math.h>

// ---------------- problem constants ----------------
constexpr int Bq   = 2;
constexpr int Lq   = 2048;
constexpr int Mq   = 2048;
constexpr int Dq   = 1024;
constexpr int DFFq = 4096;
constexpr int Hq   = 16;
constexpr int Vq   = 8192;
constexpr int NLq  = 4;
constexpr int Wwin = 512;
constexpr int NCVq = 64;
constexpr int HWLEN = Wwin + Lq;   // 2560

// ---------------- workspace layout ----------------
// fp32 region (float offsets)
constexpr size_t F_H    = 0;                        // 4M
constexpr size_t F_ATT  = F_H    + 4194304;         // 4M (attn out; later aliased as O/FF2 gemm out "abuf")
constexpr size_t F_Q    = F_ATT  + 4194304;         // 4M
constexpr size_t F_HW   = F_Q    + 4194304;         // 5M
constexpr size_t F_KW   = F_HW   + 5242880;         // 5M
constexpr size_t F_VW   = F_KW   + 5242880;         // 5M
constexpr size_t F_COMP = F_VW   + 5242880;         // 131072
constexpr size_t F_KC   = F_COMP + 131072;
constexpr size_t F_VC   = F_KC   + 131072;
constexpr size_t F_SCC  = F_VC   + 131072;
constexpr size_t F_SCH  = F_SCC  + 65536;
constexpr size_t F_PWIN = F_SCH  + 65536;           // 524288
constexpr size_t F_KPE  = F_PWIN + 524288;          // 65536
constexpr size_t F_PWB  = F_KPE  + 65536;           // 524288
constexpr size_t F_PCB  = F_PWB  + 524288;          // 65536
constexpr size_t F_BF   = F_PCB  + 65536;           // bf16 region starts here (float offset)
// bf16 region (ushort offsets relative to base)
constexpr size_t U_WT     = 0;          // per-layer transposed weights: Wq,Wk,Wv,Wo,Wr (1M each), wf1T(4M), wf2T(4M)
constexpr size_t U_WQT    = U_WT + 0;
constexpr size_t U_WKT    = U_WT + 1048576;
constexpr size_t U_WVT    = U_WT + 2097152;
constexpr size_t U_WOT    = U_WT + 3145728;
constexpr size_t U_WRT    = U_WT + 4194304;
constexpr size_t U_WF1T   = U_WT + 5242880;
constexpr size_t U_WF2T   = U_WT + 9437184;
constexpr size_t U_HBF    = 13631488;   // 4M
constexpr size_t U_HWBF   = U_HBF + 4194304;   // 5M (also reused as attbf)
constexpr size_t U_FFBF   = U_HWBF + 5242880;  // 16M (also reused as embbf at the end)
constexpr size_t U_COMPBF = U_FFBF + 16777216; // 131072
constexpr size_t U_PWINBF = U_COMPBF + 131072; // 524288
constexpr size_t U_END    = U_PWINBF + 524288;
constexpr size_t WS_FLOATS = F_BF + (U_END + 1) / 2;   // ~50.27M floats (~201 MB)

// ---------------- helpers ----------------
__device__ __forceinline__ unsigned short f2bf(float f) {
  union { float f; unsigned u; } c; c.f = f;
  unsigned u = c.u + 0x7fffu + ((c.u >> 16) & 1u);
  return (unsigned short)(u >> 16);
}

typedef __attribute__((ext_vector_type(8))) short short8v;
typedef __attribute__((ext_vector_type(4))) float f32x4v;

#define GLOAD16(gp, lp)                                                              \
  __builtin_amdgcn_global_load_lds((const __attribute__((address_space(1))) void*)(gp), \
                                   (__attribute__((address_space(3))) void*)(lp), 16, 0, 0)

// ---------------- embed ----------------
__global__ __launch_bounds__(256) void embed_kernel(const int* __restrict__ x,
                                                    const float* __restrict__ emb,
                                                    float* __restrict__ h) {
  int i = blockIdx.x * 256 + threadIdx.x;
  int tok = i >> 10;
  int d = i & 1023;
  h[i] = emb[(size_t)x[tok] * Dq + d] * 32.0f;
}

// ---------------- sinusoidal position tables ----------------
__global__ __launch_bounds__(256) void posemb_kernel(float* __restrict__ pwin,
                                                     float* __restrict__ kpe) {
  int i = blockIdx.x * 256 + threadIdx.x;
  int row = i >> 10, col = i & 1023;
  int ii = col & 511;
  bool is_cos = col >= 512;
  float invf = (float)exp(-((double)(2 * ii) / 1024.0) * log(10000.0));
  float* dst; float pos;
  if (row < Wwin) { dst = pwin + (size_t)row * Dq + col; pos = (float)(Wwin - 1 - row); }
  else { dst = kpe + (size_t)(row - Wwin) * Dq + col; pos = (float)(NCVq - 1 - (row - Wwin)); }
  float ang = pos * invf;
  *dst = is_cos ? cosf(ang) : sinf(ang);
}

// ---------------- fp32->bf16 convert (n/4 threads of float4) ----------------
__global__ __launch_bounds__(256) void cvt_bf16_kernel(const float* __restrict__ in,
                                                       unsigned short* __restrict__ out) {
  int i = blockIdx.x * 256 + threadIdx.x;
  float4 v = ((const float4*)in)[i];
  ushort4 o;
  o.x = f2bf(v.x); o.y = f2bf(v.y); o.z = f2bf(v.z); o.w = f2bf(v.w);
  ((ushort4*)out)[i] = o;
}

// ---------------- transpose + convert: W[K][N] f32 -> Wt[N][K] bf16 ----------------
__global__ __launch_bounds__(256) void tcvt_kernel(const float* __restrict__ W,
                                                   unsigned short* __restrict__ Wt,
                                                   int K, int N) {
  __shared__ float tile[64][65];
  const int n0 = blockIdx.x * 64, k0 = blockIdx.y * 64;
  const int tr = threadIdx.x >> 6;
  const int tc = threadIdx.x & 63;
#pragma unroll
  for (int i = 0; i < 16; ++i) {
    int r = i * 4 + tr;
    tile[r][tc] = W[(size_t)(k0 + r) * N + n0 + tc];
  }
  __syncthreads();
#pragma unroll
  for (int i = 0; i < 16; ++i) {
    int r = i * 4 + tr;
    Wt[(size_t)(n0 + r) * K + k0 + tc] = f2bf(tile[tc][r]);
  }
}

// ---------------- bf16 MFMA GEMM: C[M][N] = A[M][K] @ Bt[N][K]^T ----------------
// EPI: 0 = f32 out; 1 = f32 out + bias; 2 = bf16 out, gelu(x+bias)
template<int EPI>
__global__ __launch_bounds__(256) void gemm_bf16_kernel(const unsigned short* __restrict__ A,
                                                        const unsigned short* __restrict__ Bt,
                                                        const float* __restrict__ bias,
                                                        void* __restrict__ Cout,
                                                        int M, int N, int K) {
  __shared__ unsigned short ldsA[8 * 512];
  __shared__ unsigned short ldsB[8 * 512];
  const int t = threadIdx.x;
  const int wave = t >> 6, lane = t & 63;
  const int m0 = blockIdx.y * 128, n0 = blockIdx.x * 128;
  const int fr = lane & 15, fg = lane >> 4;
  const unsigned short* Ab = A + (size_t)(m0 + fr) * K + fg * 8;
  const unsigned short* Bb = Bt + (size_t)(n0 + fr) * K + fg * 8;
  const int wr = wave >> 1, wc = wave & 1;
  f32x4v acc[4][4];
#pragma unroll
  for (int i = 0; i < 4; ++i)
#pragma unroll
    for (int j = 0; j < 4; ++j) acc[i][j] = (f32x4v){0.f, 0.f, 0.f, 0.f};

  for (int k0 = 0; k0 < K; k0 += 32) {
    __syncthreads();                    // protect LDS from overwrite
    if (wave < 2) {
#pragma unroll
      for (int i = 0; i < 4; ++i) {
        int sb = wave * 4 + i;
        GLOAD16(Ab + (size_t)(sb * 16) * K + k0, &ldsA[sb * 512]);
      }
    } else {
#pragma unroll
      for (int i = 0; i < 4; ++i) {
        int sb = (wave - 2) * 4 + i;
        GLOAD16(Bb + (size_t)(sb * 16) * K + k0, &ldsB[sb * 512]);
      }
    }
    __syncthreads();                    // loads visible (barrier drains vmcnt)
    short8v af[4], bf[4];
#pragma unroll
    for (int i = 0; i < 4; ++i) {
      af[i] = *(const short8v*)&ldsA[(wr * 4 + i) * 512 + lane * 8];
      bf[i] = *(const short8v*)&ldsB[(wc * 4 + i) * 512 + lane * 8];
    }
#pragma unroll
    for (int i = 0; i < 4; ++i)
#pragma unroll
      for (int j = 0; j < 4; ++j)
        acc[i][j] = __builtin_amdgcn_mfma_f32_16x16x32_bf16(af[i], bf[j], acc[i][j], 0, 0, 0);
  }

  const int orow0 = m0 + wr * 64 + (lane >> 4) * 4;
  const int ocol0 = n0 + wc * 64 + (lane & 15);
#pragma unroll
  for (int i = 0; i < 4; ++i) {
#pragma unroll
    for (int j = 0; j < 4; ++j) {
      const int col = ocol0 + j * 16;
      float bv = (EPI >= 1) ? bias[col] : 0.f;
#pragma unroll
      for (int r = 0; r < 4; ++r) {
        const int row = orow0 + i * 16 + r;
        float v = acc[i][j][r] + bv;
        if (EPI == 2) {
          v = 0.5f * v * (1.0f + erff(v * 0.70710678118654752f));
          ((unsigned short*)Cout)[(size_t)row * N + col] = f2bf(v);
        } else {
          ((float*)Cout)[(size_t)row * N + col] = v;
        }
      }
    }
  }
}

// ---------------- fp32 tiled GEMM (kept for tiny/odd shapes) ----------------
template<int BT, int EPI>
__global__ __launch_bounds__(256) void gemm_kernel(const float* __restrict__ A,
                                                   const float* __restrict__ Bm,
                                                   const float* __restrict__ bias,
                                                   float* __restrict__ C,
                                                   int M, int N, int K) {
  __shared__ float As[16][64];
  __shared__ float Bs[16][64];
  const int tid = threadIdx.x;
  const int tx = tid & 15;
  const int ty = tid >> 4;
  const int m0 = blockIdx.y * 64;
  const int n0 = blockIdx.x * 64;
  const int ar = tid >> 2;
  const int ak = (tid & 3) << 2;
  float acc[4][4] = {};
  for (int k0 = 0; k0 < K; k0 += 16) {
    float4 av = *(const float4*)(A + (size_t)(m0 + ar) * K + (k0 + ak));
    As[ak + 0][ar] = av.x; As[ak + 1][ar] = av.y;
    As[ak + 2][ar] = av.z; As[ak + 3][ar] = av.w;
    if (BT == 0) {
      const int bk = tid >> 4;
      const int bc = (tid & 15) << 2;
      float4 bv = make_float4(0.f, 0.f, 0.f, 0.f);
      if (n0 + bc < N) bv = *(const float4*)(Bm + (size_t)(k0 + bk) * N + (n0 + bc));
      Bs[bk][bc + 0] = bv.x; Bs[bk][bc + 1] = bv.y;
      Bs[bk][bc + 2] = bv.z; Bs[bk][bc + 3] = bv.w;
    } else {
      const int c = tid >> 2;
      const int kk = (tid & 3) << 2;
      float4 bv = make_float4(0.f, 0.f, 0.f, 0.f);
      if (n0 + c < N) bv = *(const float4*)(Bm + (size_t)(n0 + c) * K + (k0 + kk));
      Bs[kk + 0][c] = bv.x; Bs[kk + 1][c] = bv.y;
      Bs[kk + 2][c] = bv.z; Bs[kk + 3][c] = bv.w;
    }
    __syncthreads();
#pragma unroll
    for (int k = 0; k < 16; ++k) {
      float4 a4 = *(const float4*)&As[k][ty << 2];
      float4 b4 = *(const float4*)&Bs[k][tx << 2];
      float aa[4] = {a4.x, a4.y, a4.z, a4.w};
      float bb[4] = {b4.x, b4.y, b4.z, b4.w};
#pragma unroll
      for (int i = 0; i < 4; ++i)
#pragma unroll
        for (int j = 0; j < 4; ++j) acc[i][j] += aa[i] * bb[j];
    }
    __syncthreads();
  }
  const int cbase = n0 + (tx << 2);
  if (cbase < N) {
#pragma unroll
    for (int i = 0; i < 4; ++i) {
      const int r = m0 + (ty << 2) + i;
      float4 o;
      float* op = &o.x;
#pragma unroll
      for (int j = 0; j < 4; ++j) {
        float v = acc[i][j];
        if (EPI >= 1) v += bias[cbase + j];
        if (EPI == 2) v = 0.5f * v * (1.0f + erff(v * 0.70710678118654752f));
        op[j] = v;
      }
      *(float4*)(C + (size_t)r * N + cbase) = o;
    }
  }
}

// ---------------- LayerNorm (row 1024), optional residual ----------------
__global__ __launch_bounds__(256) void ln_kernel(const float* __restrict__ x,
                                                 const float* __restrict__ res,
                                                 const float* __restrict__ g,
                                                 const float* __restrict__ b,
                                                 float* __restrict__ out) {
  __shared__ float sm[4];
  const int row = blockIdx.x;
  const int t = threadIdx.x;
  const float* xp = x + (size_t)row * Dq;
  float v[4];
#pragma unroll
  for (int i = 0; i < 4; ++i) v[i] = xp[t + 256 * i];
  if (res) {
    const float* rp = res + (size_t)row * Dq;
#pragma unroll
    for (int i = 0; i < 4; ++i) v[i] += rp[t + 256 * i];
  }
  float s = v[0] + v[1] + v[2] + v[3];
#pragma unroll
  for (int off = 32; off > 0; off >>= 1) s += __shfl_down(s, off);
  if ((t & 63) == 0) sm[t >> 6] = s;
  __syncthreads();
  const float mu = (sm[0] + sm[1] + sm[2] + sm[3]) * (1.0f / Dq);
  __syncthreads();
  float s2 = 0.f;
#pragma unroll
  for (int i = 0; i < 4; ++i) { float d = v[i] - mu; s2 += d * d; }
#pragma unroll
  for (int off = 32; off > 0; off >>= 1) s2 += __shfl_down(s2, off);
  if ((t & 63) == 0) sm[t >> 6] = s2;
  __syncthreads();
  const float var = (sm[0] + sm[1] + sm[2] + sm[3]) * (1.0f / Dq);
  const float rstd = rsqrtf(var + 1e-5f);
  float* op = out + (size_t)row * Dq;
#pragma unroll
  for (int i = 0; i < 4; ++i) {
    int c = t + 256 * i;
    op[c] = (v[i] - mu) * rstd * g[c] + b[c];
  }
}

// ---------------- compress ----------------
__global__ __launch_bounds__(64) void compress_kernel(const float* __restrict__ scc,
                                                      const float* __restrict__ sch,
                                                      const float* __restrict__ cache_l,
                                                      const float* __restrict__ h,
                                                      float* __restrict__ comp) {
  const int bi = blockIdx.x;
  const int head = bi & 15;
  const int c = (bi >> 4) & 63;
  const int b = bi >> 10;
  const bool from_cache = c < 32;
  const int cc = from_cache ? c : c - 32;
  const float* logits = (from_cache ? scc : sch) + (size_t)(b * 2048 + cc * 64) * 16 + head;
  const float* seq = (from_cache ? cache_l : h) + (size_t)(b * 2048 + cc * 64) * Dq + head * 64;
  __shared__ float wsm[64];
  const int t = threadIdx.x;
  wsm[t] = logits[(size_t)t * 16];
  __syncthreads();
  float mx = -1e30f;
#pragma unroll 8
  for (int s = 0; s < 64; ++s) mx = fmaxf(mx, wsm[s]);
  float sum = 0.f;
#pragma unroll 8
  for (int s = 0; s < 64; ++s) sum += expf(wsm[s] - mx);
  float myw = expf(wsm[t] - mx) / sum;
  __syncthreads();
  wsm[t] = myw;
  __syncthreads();
  float acc = 0.f;
#pragma unroll 4
  for (int s = 0; s < 64; ++s) acc += wsm[s] * seq[(size_t)s * Dq + t];
  comp[(size_t)(b * 64 + c) * Dq + head * 64 + t] = acc;
}

// ---------------- hw = concat(cache[:, -W:], h) ----------------
__global__ __launch_bounds__(256) void hwbuild_kernel(const float* __restrict__ cache_l,
                                                      const float* __restrict__ h,
                                                      float* __restrict__ hw) {
  int i = blockIdx.x * 256 + threadIdx.x;
  const int D4 = Dq / 4;
  int d4 = i % D4;
  int r = (i / D4) % HWLEN;
  int b = i / (HWLEN * D4);
  const float4* src;
  if (r < Wwin) src = (const float4*)(cache_l + (size_t)(b * Mq + (Mq - Wwin) + r) * Dq) + d4;
  else          src = (const float4*)(h + (size_t)(b * Lq + (r - Wwin)) * Dq) + d4;
  ((float4*)hw)[i] = *src;
}

// ---------------- fused long-short attention (fp32, 1024 threads) ----------------
// __launch_bounds__(1024, 4): LDS (107 KB) caps us at 1 block/CU = 16 waves = 4 waves/EU.
// Declaring exactly that stops hipcc from allocating 64 VGPRs (8-waves/EU heuristic) and
// spilling ~16 GB of scratch traffic to HBM (R5 counters: WRITE_SIZE 10.6 GB, VGPR 64).
// Swizzle (row&15)<<2: 16 offset classes -> 4-way bank conflict on the row-read dot loops
// (was (row&7)<<2 = 8-way; m136: 2.94x -> 1.58x).
__global__ __launch_bounds__(1024, 4) void attn_kernel(const float* __restrict__ q,
                                                       const float* __restrict__ kw,
                                                       const float* __restrict__ vw,
                                                       const float* __restrict__ kc,
                                                       const float* __restrict__ vc,
                                                       const float* __restrict__ Pw,
                                                       const float* __restrict__ Pc,
                                                       const float* __restrict__ rw,
                                                       const float* __restrict__ rr,
                                                       float* __restrict__ att) {
  __shared__ float qws[32][64];
  __shared__ float qrs[32][64];
  __shared__ float sc[32][580];
  __shared__ float ksf[4096];
  const int blk = blockIdx.x;
  const int qblk = blk & 63;
  const int hh = (blk >> 6) & 15;
  const int b = blk >> 10;
  const int qbase = qblk * 32;
  const int qc = qblk >> 1;
  const int t = threadIdx.x;
  const int hoff = hh * 64;

#pragma unroll
  for (int i = 0; i < 2; ++i) {
    int e = t + 1024 * i;
    int qi = e >> 6, d = e & 63;
    float qv = q[(size_t)(b * Lq + qbase + qi) * Dq + hoff + d] * 0.125f;
    qws[qi][d] = qv + rw[hoff + d];
    qrs[qi][d] = qv + rr[hoff + d];
  }
  __syncthreads();

  const int eq = t >> 6;   // wave 0..15
  const int ed = t & 63;   // lane

  // ---- Phase A: sc[qi][j] = qr . Pw[j]
  for (int cb = 0; cb < 8; ++cb) {
#pragma unroll
    for (int i = 0; i < 4; ++i) {
      int e = t + 1024 * i;
      int jj = e >> 6, d = e & 63;
      ksf[jj * 64 + (d ^ ((jj & 15) << 2))] = Pw[(size_t)(cb * 64 + jj) * Dq + hoff + d];
    }
    __syncthreads();
#pragma unroll
    for (int rs = 0; rs < 2; ++rs) {
      int qi = eq + 16 * rs;
      float dot = 0.f;
#pragma unroll
      for (int d0 = 0; d0 < 64; d0 += 4) {
        float4 qv = *(const float4*)&qrs[qi][d0];
        float4 kv = *(const float4*)&ksf[ed * 64 + (d0 ^ ((ed & 15) << 2))];
        dot += qv.x * kv.x + qv.y * kv.y + qv.z * kv.z + qv.w * kv.w;
      }
      sc[qi][cb * 64 + ed] = dot;
    }
    __syncthreads();
  }

  // ---- Phase B: sc[qi][j] += qw . kw[l+1+j]
  for (int ci = 0; ci < 9; ++ci) {
    const int khw0 = qbase + 1 + ci * 64;
#pragma unroll
    for (int i = 0; i < 4; ++i) {
      int e = t + 1024 * i;
      int kk = e >> 6, d = e & 63;
      int khw = khw0 + kk; if (khw > HWLEN - 1) khw = HWLEN - 1;
      ksf[kk * 64 + (d ^ ((kk & 15) << 2))] = kw[(size_t)(b * HWLEN + khw) * Dq + hoff + d];
    }
    __syncthreads();
#pragma unroll
    for (int rs = 0; rs < 2; ++rs) {
      int qi = eq + 16 * rs;
      int j = ci * 64 + ed - qi;
      if (j >= 0 && j < 512) {
        float dot = 0.f;
#pragma unroll
        for (int d0 = 0; d0 < 64; d0 += 4) {
          float4 qv = *(const float4*)&qws[qi][d0];
          float4 kv = *(const float4*)&ksf[ed * 64 + (d0 ^ ((ed & 15) << 2))];
          dot += qv.x * kv.x + qv.y * kv.y + qv.z * kv.z + qv.w * kv.w;
        }
        sc[qi][j] += dot;
      }
    }
    __syncthreads();
  }

  // ---- Phase C1: compressed key dots
  {
#pragma unroll
    for (int i = 0; i < 4; ++i) {
      int e = t + 1024 * i;
      int cc = e >> 6, d = e & 63;
      ksf[cc * 64 + (d ^ ((cc & 15) << 2))] = kc[(size_t)(b * 64 + cc) * Dq + hoff + d];
    }
    __syncthreads();
#pragma unroll
    for (int rs = 0; rs < 2; ++rs) {
      int qi = eq + 16 * rs;
      float dot = 0.f;
#pragma unroll
      for (int d0 = 0; d0 < 64; d0 += 4) {
        float4 qv = *(const float4*)&qws[qi][d0];
        float4 kv = *(const float4*)&ksf[ed * 64 + (d0 ^ ((ed & 15) << 2))];
        dot += qv.x * kv.x + qv.y * kv.y + qv.z * kv.z + qv.w * kv.w;
      }
      sc[qi][512 + ed] = dot;
    }
    __syncthreads();
  }
  // ---- Phase C2: compressed positional bias + causal mask
  {
#pragma unroll
    for (int i = 0; i < 4; ++i) {
      int e = t + 1024 * i;
      int cc = e >> 6, d = e & 63;
      int pidx = 31 - qc + cc;
      pidx = pidx < 0 ? 0 : (pidx > 63 ? 63 : pidx);
      ksf[cc * 64 + (d ^ ((cc & 15) << 2))] = Pc[(size_t)pidx * Dq + hoff + d];
    }
    __syncthreads();
#pragma unroll
    for (int rs = 0; rs < 2; ++rs) {
      int qi = eq + 16 * rs;
      float dot = 0.f;
#pragma unroll
      for (int d0 = 0; d0 < 64; d0 += 4) {
        float4 qv = *(const float4*)&qrs[qi][d0];
        float4 kv = *(const float4*)&ksf[ed * 64 + (d0 ^ ((ed & 15) << 2))];
        dot += qv.x * kv.x + qv.y * kv.y + qv.z * kv.z + qv.w * kv.w;
      }
      float vvv = sc[qi][512 + ed] + dot;
      sc[qi][512 + ed] = (ed >= qc + 32) ? -1e30f : vvv;
    }
    __syncthreads();
  }

  // ---- Phase D: softmax over 576 per row (32 lanes per row)
  {
    const int row = t >> 5;
    const int sub = t & 31;
    float m = -1e30f;
#pragma unroll
    for (int k = 0; k < 18; ++k) m = fmaxf(m, sc[row][sub + 32 * k]);
#pragma unroll
    for (int off = 1; off < 32; off <<= 1) m = fmaxf(m, __shfl_xor(m, off, 32));
    float ssum = 0.f;
#pragma unroll
    for (int k = 0; k < 18; ++k) {
      float p = expf(sc[row][sub + 32 * k] - m);
      sc[row][sub + 32 * k] = p;
      ssum += p;
    }
#pragma unroll
    for (int off = 1; off < 32; off <<= 1) ssum += __shfl_xor(ssum, off, 32);
    const float inv = 1.0f / ssum;
#pragma unroll
    for (int k = 0; k < 18; ++k) sc[row][sub + 32 * k] *= inv;
  }
  __syncthreads();

  // ---- Phase E: out = P_win @ Vwin + P_comp @ Vcomp (V staged in LDS per chunk)
  float acc0 = 0.f, acc1 = 0.f;
  for (int ci = 0; ci < 9; ++ci) {
    const int khw0 = qbase + 1 + ci * 64;
#pragma unroll
    for (int i = 0; i < 4; ++i) {
      int e = t + 1024 * i;
      int kk = e >> 6, d = e & 63;
      int khw = khw0 + kk; if (khw > HWLEN - 1) khw = HWLEN - 1;
      ksf[kk * 64 + (d ^ ((kk & 15) << 2))] = vw[(size_t)(b * HWLEN + khw) * Dq + hoff + d];
    }
    __syncthreads();
#pragma unroll
    for (int rs = 0; rs < 2; ++rs) {
      int qi = eq + 16 * rs;
      int lo = qi - ci * 64; if (lo < 0) lo = 0;
      int hi = 512 + qi - ci * 64; if (hi > 64) hi = 64;
      float a = 0.f;
      for (int kk = lo; kk < hi; ++kk) {
        a += sc[qi][ci * 64 + kk - qi] * ksf[kk * 64 + (ed ^ ((kk & 15) << 2))];
      }
      if (rs == 0) acc0 += a; else acc1 += a;
    }
    __syncthreads();
  }
  {
#pragma unroll
    for (int i = 0; i < 4; ++i) {
      int e = t + 1024 * i;
      int cc = e >> 6, d = e & 63;
      ksf[cc * 64 + (d ^ ((cc & 15) << 2))] = vc[(size_t)(b * 64 + cc) * Dq + hoff + d];
    }
    __syncthreads();
#pragma unroll
    for (int rs = 0; rs < 2; ++rs) {
      int qi = eq + 16 * rs;
      float a = 0.f;
      for (int cc = 0; cc < 64; ++cc) {
        a += sc[qi][512 + cc] * ksf[cc * 64 + (ed ^ ((cc & 15) << 2))];
      }
      if (rs == 0) acc0 += a; else acc1 += a;
    }
  }
  att[(size_t)(b * Lq + qbase + eq) * Dq + hoff + ed] = acc0;
  att[(size_t)(b * Lq + qbase + eq + 16) * Dq + hoff + ed] = acc1;
}

// ---------------- log_softmax in place ----------------
__global__ __launch_bounds__(256) void logsoftmax_kernel(float* __restrict__ out) {
  __shared__ float sm[4];
  const int row = blockIdx.x;
  float* p = out + (size_t)row * Vq;
  const int t = threadIdx.x;
  float v[32];
  float m = -1e30f;
#pragma unroll
  for (int i = 0; i < 32; ++i) { v[i] = p[t + 256 * i]; m = fmaxf(m, v[i]); }
#pragma unroll
  for (int off = 32; off > 0; off >>= 1) m = fmaxf(m, __shfl_xor(m, off));
  if ((t & 63) == 0) sm[t >> 6] = m;
  __syncthreads();
  m = fmaxf(fmaxf(sm[0], sm[1]), fmaxf(sm[2], sm[3]));
  __syncthreads();
  float s = 0.f;
#pragma unroll
  for (int i = 0; i < 32; ++i) s += expf(v[i] - m);
#pragma unroll
  for (int off = 32; off > 0; off >>= 1) s += __shfl_down(s, off);
  if ((t & 63) == 0) sm[t >> 6] = s;
  __syncthreads();
  const float lse = m + logf(sm[0] + sm[1] + sm[2] + sm[3]);
#pragma unroll
  for (int i = 0; i < 32; ++i) p[t + 256 * i] = v[i] - lse;
}

// ---------------- host orchestration ----------------
extern "C" void kernel_launch(void* const* d_in, const int* in_sizes, int n_in,
                              void* d_out, int out_size, void* d_ws, size_t ws_size,
                              hipStream_t stream) {
  if (ws_size < WS_FLOATS * sizeof(float)) return;

  const int*   x        = (const int*)d_in[0];
  const float* cache    = (const float*)d_in[1];
  const float* emb      = (const float*)d_in[2];
  const float* out_bias = (const float*)d_in[3];
  const float* Wqw      = (const float*)d_in[4];
  const float* Wkw      = (const float*)d_in[5];
  const float* Wvw      = (const float*)d_in[6];
  const float* Wow      = (const float*)d_in[7];
  const float* w_dc     = (const float*)d_in[8];
  const float* b_dc     = (const float*)d_in[9];
  const float* Wr       = (const float*)d_in[10];
  const float* Wrc      = (const float*)d_in[11];
  const float* brc      = (const float*)d_in[12];
  const float* rw       = (const float*)d_in[13];
  const float* rr       = (const float*)d_in[14];
  const float* g1       = (const float*)d_in[15];
  const float* b1       = (const float*)d_in[16];
  const float* g2       = (const float*)d_in[17];
  const float* b2       = (const float*)d_in[18];
  const float* gd       = (const float*)d_in[19];
  const float* bd       = (const float*)d_in[20];
  const float* gw       = (const float*)d_in[21];
  const float* bw       = (const float*)d_in[22];
  const float* wf1      = (const float*)d_in[23];
  const float* bf1      = (const float*)d_in[24];
  const float* wf2      = (const float*)d_in[25];
  const float* bf2      = (const float*)d_in[26];

  float* ws   = (float*)d_ws;
  float* hbuf = ws + F_H;
  float* attb = ws + F_ATT;
  float* abuf = ws + F_ATT;          // alias: attb is dead once attbf exists
  float* qb   = ws + F_Q;
  float* hwb  = ws + F_HW;
  float* kwb  = ws + F_KW;
  float* vwb  = ws + F_VW;
  float* comp = ws + F_COMP;
  float* kcb  = ws + F_KC;
  float* vcb  = ws + F_VC;
  float* scc  = ws + F_SCC;
  float* sch  = ws + F_SCH;
  float* pwin = ws + F_PWIN;
  float* kpe  = ws + F_KPE;
  float* Pwb  = ws + F_PWB;
  float* Pcb  = ws + F_PCB;
  unsigned short* bfb    = (unsigned short*)(ws + F_BF);
  unsigned short* WqT    = bfb + U_WQT;
  unsigned short* WkT    = bfb + U_WKT;
  unsigned short* WvT    = bfb + U_WVT;
  unsigned short* WoT    = bfb + U_WOT;
  unsigned short* WrT    = bfb + U_WRT;
  unsigned short* WF1T   = bfb + U_WF1T;
  unsigned short* WF2T   = bfb + U_WF2T;
  unsigned short* hbf    = bfb + U_HBF;
  unsigned short* hwbf   = bfb + U_HWBF;
  unsigned short* attbf  = bfb + U_HWBF;   // alias (hwbf dead by then)
  unsigned short* ffbf   = bfb + U_FFBF;
  unsigned short* embbf  = bfb + U_FFBF;   // alias (ffbf dead after last layer)
  unsigned short* compbf = bfb + U_COMPBF;
  unsigned short* pwinbf = bfb + U_PWINBF;
  float* outp = (float*)d_out;

  embed_kernel<<<(Bq * Lq * Dq) / 256, 256, 0, stream>>>(x, emb, hbuf);
  posemb_kernel<<<((Wwin + NCVq) * Dq) / 256, 256, 0, stream>>>(pwin, kpe);
  cvt_bf16_kernel<<<(Wwin * Dq) / 1024, 256, 0, stream>>>(pwin, pwinbf);

  for (int l = 0; l < NLq; ++l) {
    const float* cache_l = cache + (size_t)l * Bq * Mq * Dq;
    const float* Wq_l  = Wqw + (size_t)l * Dq * Dq;
    const float* Wk_l  = Wkw + (size_t)l * Dq * Dq;
    const float* Wv_l  = Wvw + (size_t)l * Dq * Dq;
    const float* Wo_l  = Wow + (size_t)l * Dq * Dq;
    const float* wdc_l = w_dc + (size_t)l * Dq * 16;
    const float* bdc_l = b_dc + (size_t)l * 16;
    const float* Wr_l  = Wr  + (size_t)l * Dq * Dq;
    const float* Wrc_l = Wrc + (size_t)l * Dq * Dq;
    const float* brc_l = brc + (size_t)l * Dq;
    const float* rw_l  = rw  + (size_t)l * Hq * 64;
    const float* rr_l  = rr  + (size_t)l * Hq * 64;
    const float* g1_l  = g1 + (size_t)l * Dq;  const float* b1_l = b1 + (size_t)l * Dq;
    const float* g2_l  = g2 + (size_t)l * Dq;  const float* b2_l = b2 + (size_t)l * Dq;
    const float* gd_l  = gd + (size_t)l * Dq;  const float* bd_l = bd + (size_t)l * Dq;
    const float* gw_l  = gw + (size_t)l * Dq;  const float* bw_l = bw + (size_t)l * Dq;
    const float* wf1_l = wf1 + (size_t)l * Dq * DFFq;
    const float* bf1_l = bf1 + (size_t)l * DFFq;
    const float* wf2_l = wf2 + (size_t)l * DFFq * Dq;
    const float* bf2_l = bf2 + (size_t)l * Dq;

    // weight transposes+convert for this layer
    tcvt_kernel<<<dim3(16, 16), 256, 0, stream>>>(Wq_l, WqT, Dq, Dq);
    tcvt_kernel<<<dim3(16, 16), 256, 0, stream>>>(Wk_l, WkT, Dq, Dq);
    tcvt_kernel<<<dim3(16, 16), 256, 0, stream>>>(Wv_l, WvT, Dq, Dq);
    tcvt_kernel<<<dim3(16, 16), 256, 0, stream>>>(Wo_l, WoT, Dq, Dq);
    tcvt_kernel<<<dim3(16, 16), 256, 0, stream>>>(Wr_l, WrT, Dq, Dq);
    tcvt_kernel<<<dim3(64, 16), 256, 0, stream>>>(wf1_l, WF1T, Dq, DFFq);
    tcvt_kernel<<<dim3(16, 64), 256, 0, stream>>>(wf2_l, WF2T, DFFq, Dq);

    // compression scores + compress
    gemm_kernel<0, 1><<<dim3(1, 64), 256, 0, stream>>>(cache_l, wdc_l, bdc_l, scc, Bq * Mq, 16, Dq);
    gemm_kernel<0, 1><<<dim3(1, 64), 256, 0, stream>>>(hbuf, wdc_l, bdc_l, sch, Bq * Lq, 16, Dq);
    compress_kernel<<<Bq * 64 * Hq, 64, 0, stream>>>(scc, sch, cache_l, hbuf, comp);
    cvt_bf16_kernel<<<(Bq * NCVq * Dq) / 1024, 256, 0, stream>>>(comp, compbf);
    // compressed K/V
    gemm_bf16_kernel<0><<<dim3(8, 1), 256, 0, stream>>>(compbf, WkT, nullptr, kcb, Bq * NCVq, Dq, Dq);
    ln_kernel<<<Bq * NCVq, 256, 0, stream>>>(kcb, nullptr, gd_l, bd_l, kcb);
    gemm_bf16_kernel<0><<<dim3(8, 1), 256, 0, stream>>>(compbf, WvT, nullptr, vcb, Bq * NCVq, Dq, Dq);
    ln_kernel<<<Bq * NCVq, 256, 0, stream>>>(vcb, nullptr, gd_l, bd_l, vcb);
    // window K/V
    hwbuild_kernel<<<(Bq * HWLEN * (Dq / 4)) / 256, 256, 0, stream>>>(cache_l, hbuf, hwb);
    cvt_bf16_kernel<<<(Bq * HWLEN * Dq) / 1024, 256, 0, stream>>>(hwb, hwbf);
    gemm_bf16_kernel<0><<<dim3(8, 40), 256, 0, stream>>>(hwbf, WkT, nullptr, kwb, Bq * HWLEN, Dq, Dq);
    ln_kernel<<<Bq * HWLEN, 256, 0, stream>>>(kwb, nullptr, gw_l, bw_l, kwb);
    gemm_bf16_kernel<0><<<dim3(8, 40), 256, 0, stream>>>(hwbf, WvT, nullptr, vwb, Bq * HWLEN, Dq, Dq);
    ln_kernel<<<Bq * HWLEN, 256, 0, stream>>>(vwb, nullptr, gw_l, bw_l, vwb);
    // Q and positional projections
    cvt_bf16_kernel<<<(Bq * Lq * Dq) / 1024, 256, 0, stream>>>(hbuf, hbf);
    gemm_bf16_kernel<0><<<dim3(8, 32), 256, 0, stream>>>(hbf, WqT, nullptr, qb, Bq * Lq, Dq, Dq);
    gemm_bf16_kernel<0><<<dim3(8, 4), 256, 0, stream>>>(pwinbf, WrT, nullptr, Pwb, Wwin, Dq, Dq);
    gemm_kernel<0, 1><<<dim3(16, 1), 256, 0, stream>>>(kpe, Wrc_l, brc_l, Pcb, NCVq, Dq, Dq);
    // fused attention (fp32)
    attn_kernel<<<Bq * Hq * 64, 1024, 0, stream>>>(qb, kwb, vwb, kcb, vcb, Pwb, Pcb, rw_l, rr_l, attb);
    // O projection + residual LN
    cvt_bf16_kernel<<<(Bq * Lq * Dq) / 1024, 256, 0, stream>>>(attb, attbf);
    gemm_bf16_kernel<0><<<dim3(8, 32), 256, 0, stream>>>(attbf, WoT, nullptr, abuf, Bq * Lq, Dq, Dq);
    ln_kernel<<<Bq * Lq, 256, 0, stream>>>(hbuf, abuf, g1_l, b1_l, hbuf);
    // FFN
    cvt_bf16_kernel<<<(Bq * Lq * Dq) / 1024, 256, 0, stream>>>(hbuf, hbf);
    gemm_bf16_kernel<2><<<dim3(32, 32), 256, 0, stream>>>(hbf, WF1T, bf1_l, ffbf, Bq * Lq, DFFq, Dq);
    gemm_bf16_kernel<1><<<dim3(8, 32), 256, 0, stream>>>(ffbf, WF2T, bf2_l, abuf, Bq * Lq, Dq, DFFq);
    ln_kernel<<<Bq * Lq, 256, 0, stream>>>(hbuf, abuf, g2_l, b2_l, hbuf);
  }

  // LM head + log_softmax
  cvt_bf16_kernel<<<(Bq * Lq * Dq) / 1024, 256, 0, stream>>>(hbuf, hbf);
  cvt_bf16_kernel<<<(Vq * Dq) / 1024, 256, 0, stream>>>(emb, embbf);
  gemm_bf16_kernel<1><<<dim3(Vq / 128, (Bq * Lq) / 128), 256, 0, stream>>>(hbf, embbf, out_bias,
                                                                           outp, Bq * Lq, Vq, Dq);
  logsoftmax_kernel<<<Bq * Lq, 256, 0, stream>>>(outp);
}

// Round 9
// 24112.357 us; speedup vs baseline: 1.0155x; 1.0155x over previous
//
#include <hip/hip_runtime.h>
#include <math.h>

// ---------------- problem constants ----------------
constexpr int Bq   = 2;
constexpr int Lq   = 2048;
constexpr int Mq   = 2048;
constexpr int Dq   = 1024;
constexpr int DFFq = 4096;
constexpr int Hq   = 16;
constexpr int Vq   = 8192;
constexpr int NLq  = 4;
constexpr int Wwin = 512;
constexpr int NCVq = 64;
constexpr int HWLEN = Wwin + Lq;   // 2560

// ---------------- workspace layout ----------------
// fp32 region (float offsets)
constexpr size_t F_H    = 0;                        // 4M
constexpr size_t F_ATT  = F_H    + 4194304;         // 4M (attn out; later aliased as O/FF2 gemm out "abuf")
constexpr size_t F_Q    = F_ATT  + 4194304;         // 4M
constexpr size_t F_HW   = F_Q    + 4194304;         // 5M
constexpr size_t F_KW   = F_HW   + 5242880;         // 5M
constexpr size_t F_VW   = F_KW   + 5242880;         // 5M
constexpr size_t F_COMP = F_VW   + 5242880;         // 131072
constexpr size_t F_KC   = F_COMP + 131072;
constexpr size_t F_VC   = F_KC   + 131072;
constexpr size_t F_SCC  = F_VC   + 131072;
constexpr size_t F_SCH  = F_SCC  + 65536;
constexpr size_t F_PWIN = F_SCH  + 65536;           // 524288
constexpr size_t F_KPE  = F_PWIN + 524288;          // 65536
constexpr size_t F_PWB  = F_KPE  + 65536;           // 524288
constexpr size_t F_PCB  = F_PWB  + 524288;          // 65536
constexpr size_t F_BF   = F_PCB  + 65536;           // bf16 region starts here (float offset)
// bf16 region (ushort offsets relative to base)
constexpr size_t U_WT     = 0;          // per-layer transposed weights: Wq,Wk,Wv,Wo,Wr (1M each), wf1T(4M), wf2T(4M)
constexpr size_t U_WQT    = U_WT + 0;
constexpr size_t U_WKT    = U_WT + 1048576;
constexpr size_t U_WVT    = U_WT + 2097152;
constexpr size_t U_WOT    = U_WT + 3145728;
constexpr size_t U_WRT    = U_WT + 4194304;
constexpr size_t U_WF1T   = U_WT + 5242880;
constexpr size_t U_WF2T   = U_WT + 9437184;
constexpr size_t U_HBF    = 13631488;   // 4M
constexpr size_t U_HWBF   = U_HBF + 4194304;   // 5M (also reused as attbf)
constexpr size_t U_FFBF   = U_HWBF + 5242880;  // 16M (also reused as embbf at the end)
constexpr size_t U_COMPBF = U_FFBF + 16777216; // 131072
constexpr size_t U_PWINBF = U_COMPBF + 131072; // 524288
constexpr size_t U_END    = U_PWINBF + 524288;
constexpr size_t WS_FLOATS = F_BF + (U_END + 1) / 2;   // ~50.27M floats (~201 MB)

// ---------------- helpers ----------------
__device__ __forceinline__ unsigned short f2bf(float f) {
  union { float f; unsigned u; } c; c.f = f;
  unsigned u = c.u + 0x7fffu + ((c.u >> 16) & 1u);
  return (unsigned short)(u >> 16);
}

typedef __attribute__((ext_vector_type(8))) short short8v;
typedef __attribute__((ext_vector_type(4))) float f32x4v;

#define GLOAD16(gp, lp)                                                              \
  __builtin_amdgcn_global_load_lds((const __attribute__((address_space(1))) void*)(gp), \
                                   (__attribute__((address_space(3))) void*)(lp), 16, 0, 0)

// ---------------- embed ----------------
__global__ __launch_bounds__(256) void embed_kernel(const int* __restrict__ x,
                                                    const float* __restrict__ emb,
                                                    float* __restrict__ h) {
  int i = blockIdx.x * 256 + threadIdx.x;
  int tok = i >> 10;
  int d = i & 1023;
  h[i] = emb[(size_t)x[tok] * Dq + d] * 32.0f;
}

// ---------------- sinusoidal position tables ----------------
__global__ __launch_bounds__(256) void posemb_kernel(float* __restrict__ pwin,
                                                     float* __restrict__ kpe) {
  int i = blockIdx.x * 256 + threadIdx.x;
  int row = i >> 10, col = i & 1023;
  int ii = col & 511;
  bool is_cos = col >= 512;
  float invf = (float)exp(-((double)(2 * ii) / 1024.0) * log(10000.0));
  float* dst; float pos;
  if (row < Wwin) { dst = pwin + (size_t)row * Dq + col; pos = (float)(Wwin - 1 - row); }
  else { dst = kpe + (size_t)(row - Wwin) * Dq + col; pos = (float)(NCVq - 1 - (row - Wwin)); }
  float ang = pos * invf;
  *dst = is_cos ? cosf(ang) : sinf(ang);
}

// ---------------- fp32->bf16 convert (n/4 threads of float4) ----------------
__global__ __launch_bounds__(256) void cvt_bf16_kernel(const float* __restrict__ in,
                                                       unsigned short* __restrict__ out) {
  int i = blockIdx.x * 256 + threadIdx.x;
  float4 v = ((const float4*)in)[i];
  ushort4 o;
  o.x = f2bf(v.x); o.y = f2bf(v.y); o.z = f2bf(v.z); o.w = f2bf(v.w);
  ((ushort4*)out)[i] = o;
}

// ---------------- transpose + convert: W[K][N] f32 -> Wt[N][K] bf16 ----------------
__global__ __launch_bounds__(256) void tcvt_kernel(const float* __restrict__ W,
                                                   unsigned short* __restrict__ Wt,
                                                   int K, int N) {
  __shared__ float tile[64][65];
  const int n0 = blockIdx.x * 64, k0 = blockIdx.y * 64;
  const int tr = threadIdx.x >> 6;
  const int tc = threadIdx.x & 63;
#pragma unroll
  for (int i = 0; i < 16; ++i) {
    int r = i * 4 + tr;
    tile[r][tc] = W[(size_t)(k0 + r) * N + n0 + tc];
  }
  __syncthreads();
#pragma unroll
  for (int i = 0; i < 16; ++i) {
    int r = i * 4 + tr;
    Wt[(size_t)(n0 + r) * K + k0 + tc] = f2bf(tile[tc][r]);
  }
}

// ---------------- bf16 MFMA GEMM: C[M][N] = A[M][K] @ Bt[N][K]^T ----------------
// EPI: 0 = f32 out; 1 = f32 out + bias; 2 = bf16 out, gelu(x+bias)
template<int EPI>
__global__ __launch_bounds__(256) void gemm_bf16_kernel(const unsigned short* __restrict__ A,
                                                        const unsigned short* __restrict__ Bt,
                                                        const float* __restrict__ bias,
                                                        void* __restrict__ Cout,
                                                        int M, int N, int K) {
  __shared__ unsigned short ldsA[8 * 512];
  __shared__ unsigned short ldsB[8 * 512];
  const int t = threadIdx.x;
  const int wave = t >> 6, lane = t & 63;
  const int m0 = blockIdx.y * 128, n0 = blockIdx.x * 128;
  const int fr = lane & 15, fg = lane >> 4;
  const unsigned short* Ab = A + (size_t)(m0 + fr) * K + fg * 8;
  const unsigned short* Bb = Bt + (size_t)(n0 + fr) * K + fg * 8;
  const int wr = wave >> 1, wc = wave & 1;
  f32x4v acc[4][4];
#pragma unroll
  for (int i = 0; i < 4; ++i)
#pragma unroll
    for (int j = 0; j < 4; ++j) acc[i][j] = (f32x4v){0.f, 0.f, 0.f, 0.f};

  for (int k0 = 0; k0 < K; k0 += 32) {
    __syncthreads();                    // protect LDS from overwrite
    if (wave < 2) {
#pragma unroll
      for (int i = 0; i < 4; ++i) {
        int sb = wave * 4 + i;
        GLOAD16(Ab + (size_t)(sb * 16) * K + k0, &ldsA[sb * 512]);
      }
    } else {
#pragma unroll
      for (int i = 0; i < 4; ++i) {
        int sb = (wave - 2) * 4 + i;
        GLOAD16(Bb + (size_t)(sb * 16) * K + k0, &ldsB[sb * 512]);
      }
    }
    __syncthreads();                    // loads visible (barrier drains vmcnt)
    short8v af[4], bf[4];
#pragma unroll
    for (int i = 0; i < 4; ++i) {
      af[i] = *(const short8v*)&ldsA[(wr * 4 + i) * 512 + lane * 8];
      bf[i] = *(const short8v*)&ldsB[(wc * 4 + i) * 512 + lane * 8];
    }
#pragma unroll
    for (int i = 0; i < 4; ++i)
#pragma unroll
      for (int j = 0; j < 4; ++j)
        acc[i][j] = __builtin_amdgcn_mfma_f32_16x16x32_bf16(af[i], bf[j], acc[i][j], 0, 0, 0);
  }

  const int orow0 = m0 + wr * 64 + (lane >> 4) * 4;
  const int ocol0 = n0 + wc * 64 + (lane & 15);
#pragma unroll
  for (int i = 0; i < 4; ++i) {
#pragma unroll
    for (int j = 0; j < 4; ++j) {
      const int col = ocol0 + j * 16;
      float bv = (EPI >= 1) ? bias[col] : 0.f;
#pragma unroll
      for (int r = 0; r < 4; ++r) {
        const int row = orow0 + i * 16 + r;
        float v = acc[i][j][r] + bv;
        if (EPI == 2) {
          v = 0.5f * v * (1.0f + erff(v * 0.70710678118654752f));
          ((unsigned short*)Cout)[(size_t)row * N + col] = f2bf(v);
        } else {
          ((float*)Cout)[(size_t)row * N + col] = v;
        }
      }
    }
  }
}

// ---------------- fp32 tiled GEMM (kept for tiny/odd shapes) ----------------
template<int BT, int EPI>
__global__ __launch_bounds__(256) void gemm_kernel(const float* __restrict__ A,
                                                   const float* __restrict__ Bm,
                                                   const float* __restrict__ bias,
                                                   float* __restrict__ C,
                                                   int M, int N, int K) {
  __shared__ float As[16][64];
  __shared__ float Bs[16][64];
  const int tid = threadIdx.x;
  const int tx = tid & 15;
  const int ty = tid >> 4;
  const int m0 = blockIdx.y * 64;
  const int n0 = blockIdx.x * 64;
  const int ar = tid >> 2;
  const int ak = (tid & 3) << 2;
  float acc[4][4] = {};
  for (int k0 = 0; k0 < K; k0 += 16) {
    float4 av = *(const float4*)(A + (size_t)(m0 + ar) * K + (k0 + ak));
    As[ak + 0][ar] = av.x; As[ak + 1][ar] = av.y;
    As[ak + 2][ar] = av.z; As[ak + 3][ar] = av.w;
    if (BT == 0) {
      const int bk = tid >> 4;
      const int bc = (tid & 15) << 2;
      float4 bv = make_float4(0.f, 0.f, 0.f, 0.f);
      if (n0 + bc < N) bv = *(const float4*)(Bm + (size_t)(k0 + bk) * N + (n0 + bc));
      Bs[bk][bc + 0] = bv.x; Bs[bk][bc + 1] = bv.y;
      Bs[bk][bc + 2] = bv.z; Bs[bk][bc + 3] = bv.w;
    } else {
      const int c = tid >> 2;
      const int kk = (tid & 3) << 2;
      float4 bv = make_float4(0.f, 0.f, 0.f, 0.f);
      if (n0 + c < N) bv = *(const float4*)(Bm + (size_t)(n0 + c) * K + (k0 + kk));
      Bs[kk + 0][c] = bv.x; Bs[kk + 1][c] = bv.y;
      Bs[kk + 2][c] = bv.z; Bs[kk + 3][c] = bv.w;
    }
    __syncthreads();
#pragma unroll
    for (int k = 0; k < 16; ++k) {
      float4 a4 = *(const float4*)&As[k][ty << 2];
      float4 b4 = *(const float4*)&Bs[k][tx << 2];
      float aa[4] = {a4.x, a4.y, a4.z, a4.w};
      float bb[4] = {b4.x, b4.y, b4.z, b4.w};
#pragma unroll
      for (int i = 0; i < 4; ++i)
#pragma unroll
        for (int j = 0; j < 4; ++j) acc[i][j] += aa[i] * bb[j];
    }
    __syncthreads();
  }
  const int cbase = n0 + (tx << 2);
  if (cbase < N) {
#pragma unroll
    for (int i = 0; i < 4; ++i) {
      const int r = m0 + (ty << 2) + i;
      float4 o;
      float* op = &o.x;
#pragma unroll
      for (int j = 0; j < 4; ++j) {
        float v = acc[i][j];
        if (EPI >= 1) v += bias[cbase + j];
        if (EPI == 2) v = 0.5f * v * (1.0f + erff(v * 0.70710678118654752f));
        op[j] = v;
      }
      *(float4*)(C + (size_t)r * N + cbase) = o;
    }
  }
}

// ---------------- LayerNorm (row 1024), optional residual ----------------
__global__ __launch_bounds__(256) void ln_kernel(const float* __restrict__ x,
                                                 const float* __restrict__ res,
                                                 const float* __restrict__ g,
                                                 const float* __restrict__ b,
                                                 float* __restrict__ out) {
  __shared__ float sm[4];
  const int row = blockIdx.x;
  const int t = threadIdx.x;
  const float* xp = x + (size_t)row * Dq;
  float v[4];
#pragma unroll
  for (int i = 0; i < 4; ++i) v[i] = xp[t + 256 * i];
  if (res) {
    const float* rp = res + (size_t)row * Dq;
#pragma unroll
    for (int i = 0; i < 4; ++i) v[i] += rp[t + 256 * i];
  }
  float s = v[0] + v[1] + v[2] + v[3];
#pragma unroll
  for (int off = 32; off > 0; off >>= 1) s += __shfl_down(s, off);
  if ((t & 63) == 0) sm[t >> 6] = s;
  __syncthreads();
  const float mu = (sm[0] + sm[1] + sm[2] + sm[3]) * (1.0f / Dq);
  __syncthreads();
  float s2 = 0.f;
#pragma unroll
  for (int i = 0; i < 4; ++i) { float d = v[i] - mu; s2 += d * d; }
#pragma unroll
  for (int off = 32; off > 0; off >>= 1) s2 += __shfl_down(s2, off);
  if ((t & 63) == 0) sm[t >> 6] = s2;
  __syncthreads();
  const float var = (sm[0] + sm[1] + sm[2] + sm[3]) * (1.0f / Dq);
  const float rstd = rsqrtf(var + 1e-5f);
  float* op = out + (size_t)row * Dq;
#pragma unroll
  for (int i = 0; i < 4; ++i) {
    int c = t + 256 * i;
    op[c] = (v[i] - mu) * rstd * g[c] + b[c];
  }
}

// ---------------- compress ----------------
__global__ __launch_bounds__(64) void compress_kernel(const float* __restrict__ scc,
                                                      const float* __restrict__ sch,
                                                      const float* __restrict__ cache_l,
                                                      const float* __restrict__ h,
                                                      float* __restrict__ comp) {
  const int bi = blockIdx.x;
  const int head = bi & 15;
  const int c = (bi >> 4) & 63;
  const int b = bi >> 10;
  const bool from_cache = c < 32;
  const int cc = from_cache ? c : c - 32;
  const float* logits = (from_cache ? scc : sch) + (size_t)(b * 2048 + cc * 64) * 16 + head;
  const float* seq = (from_cache ? cache_l : h) + (size_t)(b * 2048 + cc * 64) * Dq + head * 64;
  __shared__ float wsm[64];
  const int t = threadIdx.x;
  wsm[t] = logits[(size_t)t * 16];
  __syncthreads();
  float mx = -1e30f;
#pragma unroll 8
  for (int s = 0; s < 64; ++s) mx = fmaxf(mx, wsm[s]);
  float sum = 0.f;
#pragma unroll 8
  for (int s = 0; s < 64; ++s) sum += expf(wsm[s] - mx);
  float myw = expf(wsm[t] - mx) / sum;
  __syncthreads();
  wsm[t] = myw;
  __syncthreads();
  float acc = 0.f;
#pragma unroll 4
  for (int s = 0; s < 64; ++s) acc += wsm[s] * seq[(size_t)s * Dq + t];
  comp[(size_t)(b * 64 + c) * Dq + head * 64 + t] = acc;
}

// ---------------- hw = concat(cache[:, -W:], h) ----------------
__global__ __launch_bounds__(256) void hwbuild_kernel(const float* __restrict__ cache_l,
                                                      const float* __restrict__ h,
                                                      float* __restrict__ hw) {
  int i = blockIdx.x * 256 + threadIdx.x;
  const int D4 = Dq / 4;
  int d4 = i % D4;
  int r = (i / D4) % HWLEN;
  int b = i / (HWLEN * D4);
  const float4* src;
  if (r < Wwin) src = (const float4*)(cache_l + (size_t)(b * Mq + (Mq - Wwin) + r) * Dq) + d4;
  else          src = (const float4*)(h + (size_t)(b * Lq + (r - Wwin)) * Dq) + d4;
  ((float4*)hw)[i] = *src;
}

// ---------------- fused long-short attention (fp32, 1024 threads) ----------------
// R8 post-mortem: __launch_bounds__(1024, 4) did NOT raise the VGPR cap (VGPR stayed 64,
// scratch traffic stayed 16.6 GB/dispatch = the whole 5.2 ms). Mechanism: the 2nd
// launch_bounds arg sets only the MIN of amdgpu-waves-per-eu; the allocator targets the
// range MAX (default 8/EU) -> 64-VGPR cap -> ~5 KB/thread spill. Fix: pin the range with
// amdgpu_waves_per_eu(4,4). LDS (107 KB) caps us at 1 block/CU = 4 waves/EU anyway, so
// (4,4) costs nothing and raises the budget to 512/4 = 128 VGPRs.
__global__ __attribute__((amdgpu_waves_per_eu(4, 4)))
__launch_bounds__(1024) void attn_kernel(const float* __restrict__ q,
                                         const float* __restrict__ kw,
                                         const float* __restrict__ vw,
                                         const float* __restrict__ kc,
                                         const float* __restrict__ vc,
                                         const float* __restrict__ Pw,
                                         const float* __restrict__ Pc,
                                         const float* __restrict__ rw,
                                         const float* __restrict__ rr,
                                         float* __restrict__ att) {
  __shared__ float qws[32][64];
  __shared__ float qrs[32][64];
  __shared__ float sc[32][580];
  __shared__ float ksf[4096];
  const int blk = blockIdx.x;
  const int qblk = blk & 63;
  const int hh = (blk >> 6) & 15;
  const int b = blk >> 10;
  const int qbase = qblk * 32;
  const int qc = qblk >> 1;
  const int t = threadIdx.x;
  const int hoff = hh * 64;

#pragma unroll
  for (int i = 0; i < 2; ++i) {
    int e = t + 1024 * i;
    int qi = e >> 6, d = e & 63;
    float qv = q[(size_t)(b * Lq + qbase + qi) * Dq + hoff + d] * 0.125f;
    qws[qi][d] = qv + rw[hoff + d];
    qrs[qi][d] = qv + rr[hoff + d];
  }
  __syncthreads();

  const int eq = t >> 6;   // wave 0..15
  const int ed = t & 63;   // lane

  // ---- Phase A: sc[qi][j] = qr . Pw[j]
  for (int cb = 0; cb < 8; ++cb) {
#pragma unroll
    for (int i = 0; i < 4; ++i) {
      int e = t + 1024 * i;
      int jj = e >> 6, d = e & 63;
      ksf[jj * 64 + (d ^ ((jj & 15) << 2))] = Pw[(size_t)(cb * 64 + jj) * Dq + hoff + d];
    }
    __syncthreads();
#pragma unroll
    for (int rs = 0; rs < 2; ++rs) {
      int qi = eq + 16 * rs;
      float dot = 0.f;
#pragma unroll
      for (int d0 = 0; d0 < 64; d0 += 4) {
        float4 qv = *(const float4*)&qrs[qi][d0];
        float4 kv = *(const float4*)&ksf[ed * 64 + (d0 ^ ((ed & 15) << 2))];
        dot += qv.x * kv.x + qv.y * kv.y + qv.z * kv.z + qv.w * kv.w;
      }
      sc[qi][cb * 64 + ed] = dot;
    }
    __syncthreads();
  }

  // ---- Phase B: sc[qi][j] += qw . kw[l+1+j]
  for (int ci = 0; ci < 9; ++ci) {
    const int khw0 = qbase + 1 + ci * 64;
#pragma unroll
    for (int i = 0; i < 4; ++i) {
      int e = t + 1024 * i;
      int kk = e >> 6, d = e & 63;
      int khw = khw0 + kk; if (khw > HWLEN - 1) khw = HWLEN - 1;
      ksf[kk * 64 + (d ^ ((kk & 15) << 2))] = kw[(size_t)(b * HWLEN + khw) * Dq + hoff + d];
    }
    __syncthreads();
#pragma unroll
    for (int rs = 0; rs < 2; ++rs) {
      int qi = eq + 16 * rs;
      int j = ci * 64 + ed - qi;
      if (j >= 0 && j < 512) {
        float dot = 0.f;
#pragma unroll
        for (int d0 = 0; d0 < 64; d0 += 4) {
          float4 qv = *(const float4*)&qws[qi][d0];
          float4 kv = *(const float4*)&ksf[ed * 64 + (d0 ^ ((ed & 15) << 2))];
          dot += qv.x * kv.x + qv.y * kv.y + qv.z * kv.z + qv.w * kv.w;
        }
        sc[qi][j] += dot;
      }
    }
    __syncthreads();
  }

  // ---- Phase C1: compressed key dots
  {
#pragma unroll
    for (int i = 0; i < 4; ++i) {
      int e = t + 1024 * i;
      int cc = e >> 6, d = e & 63;
      ksf[cc * 64 + (d ^ ((cc & 15) << 2))] = kc[(size_t)(b * 64 + cc) * Dq + hoff + d];
    }
    __syncthreads();
#pragma unroll
    for (int rs = 0; rs < 2; ++rs) {
      int qi = eq + 16 * rs;
      float dot = 0.f;
#pragma unroll
      for (int d0 = 0; d0 < 64; d0 += 4) {
        float4 qv = *(const float4*)&qws[qi][d0];
        float4 kv = *(const float4*)&ksf[ed * 64 + (d0 ^ ((ed & 15) << 2))];
        dot += qv.x * kv.x + qv.y * kv.y + qv.z * kv.z + qv.w * kv.w;
      }
      sc[qi][512 + ed] = dot;
    }
    __syncthreads();
  }
  // ---- Phase C2: compressed positional bias + causal mask
  {
#pragma unroll
    for (int i = 0; i < 4; ++i) {
      int e = t + 1024 * i;
      int cc = e >> 6, d = e & 63;
      int pidx = 31 - qc + cc;
      pidx = pidx < 0 ? 0 : (pidx > 63 ? 63 : pidx);
      ksf[cc * 64 + (d ^ ((cc & 15) << 2))] = Pc[(size_t)pidx * Dq + hoff + d];
    }
    __syncthreads();
#pragma unroll
    for (int rs = 0; rs < 2; ++rs) {
      int qi = eq + 16 * rs;
      float dot = 0.f;
#pragma unroll
      for (int d0 = 0; d0 < 64; d0 += 4) {
        float4 qv = *(const float4*)&qrs[qi][d0];
        float4 kv = *(const float4*)&ksf[ed * 64 + (d0 ^ ((ed & 15) << 2))];
        dot += qv.x * kv.x + qv.y * kv.y + qv.z * kv.z + qv.w * kv.w;
      }
      float vvv = sc[qi][512 + ed] + dot;
      sc[qi][512 + ed] = (ed >= qc + 32) ? -1e30f : vvv;
    }
    __syncthreads();
  }

  // ---- Phase D: softmax over 576 per row (32 lanes per row)
  {
    const int row = t >> 5;
    const int sub = t & 31;
    float m = -1e30f;
#pragma unroll
    for (int k = 0; k < 18; ++k) m = fmaxf(m, sc[row][sub + 32 * k]);
#pragma unroll
    for (int off = 1; off < 32; off <<= 1) m = fmaxf(m, __shfl_xor(m, off, 32));
    float ssum = 0.f;
#pragma unroll
    for (int k = 0; k < 18; ++k) {
      float p = expf(sc[row][sub + 32 * k] - m);
      sc[row][sub + 32 * k] = p;
      ssum += p;
    }
#pragma unroll
    for (int off = 1; off < 32; off <<= 1) ssum += __shfl_xor(ssum, off, 32);
    const float inv = 1.0f / ssum;
#pragma unroll
    for (int k = 0; k < 18; ++k) sc[row][sub + 32 * k] *= inv;
  }
  __syncthreads();

  // ---- Phase E: out = P_win @ Vwin + P_comp @ Vcomp (V staged in LDS per chunk)
  float acc0 = 0.f, acc1 = 0.f;
  for (int ci = 0; ci < 9; ++ci) {
    const int khw0 = qbase + 1 + ci * 64;
#pragma unroll
    for (int i = 0; i < 4; ++i) {
      int e = t + 1024 * i;
      int kk = e >> 6, d = e & 63;
      int khw = khw0 + kk; if (khw > HWLEN - 1) khw = HWLEN - 1;
      ksf[kk * 64 + (d ^ ((kk & 15) << 2))] = vw[(size_t)(b * HWLEN + khw) * Dq + hoff + d];
    }
    __syncthreads();
#pragma unroll
    for (int rs = 0; rs < 2; ++rs) {
      int qi = eq + 16 * rs;
      int lo = qi - ci * 64; if (lo < 0) lo = 0;
      int hi = 512 + qi - ci * 64; if (hi > 64) hi = 64;
      float a = 0.f;
      for (int kk = lo; kk < hi; ++kk) {
        a += sc[qi][ci * 64 + kk - qi] * ksf[kk * 64 + (ed ^ ((kk & 15) << 2))];
      }
      if (rs == 0) acc0 += a; else acc1 += a;
    }
    __syncthreads();
  }
  {
#pragma unroll
    for (int i = 0; i < 4; ++i) {
      int e = t + 1024 * i;
      int cc = e >> 6, d = e & 63;
      ksf[cc * 64 + (d ^ ((cc & 15) << 2))] = vc[(size_t)(b * 64 + cc) * Dq + hoff + d];
    }
    __syncthreads();
#pragma unroll
    for (int rs = 0; rs < 2; ++rs) {
      int qi = eq + 16 * rs;
      float a = 0.f;
      for (int cc = 0; cc < 64; ++cc) {
        a += sc[qi][512 + cc] * ksf[cc * 64 + (ed ^ ((cc & 15) << 2))];
      }
      if (rs == 0) acc0 += a; else acc1 += a;
    }
  }
  att[(size_t)(b * Lq + qbase + eq) * Dq + hoff + ed] = acc0;
  att[(size_t)(b * Lq + qbase + eq + 16) * Dq + hoff + ed] = acc1;
}

// ---------------- log_softmax in place ----------------
__global__ __launch_bounds__(256) void logsoftmax_kernel(float* __restrict__ out) {
  __shared__ float sm[4];
  const int row = blockIdx.x;
  float* p = out + (size_t)row * Vq;
  const int t = threadIdx.x;
  float v[32];
  float m = -1e30f;
#pragma unroll
  for (int i = 0; i < 32; ++i) { v[i] = p[t + 256 * i]; m = fmaxf(m, v[i]); }
#pragma unroll
  for (int off = 32; off > 0; off >>= 1) m = fmaxf(m, __shfl_xor(m, off));
  if ((t & 63) == 0) sm[t >> 6] = m;
  __syncthreads();
  m = fmaxf(fmaxf(sm[0], sm[1]), fmaxf(sm[2], sm[3]));
  __syncthreads();
  float s = 0.f;
#pragma unroll
  for (int i = 0; i < 32; ++i) s += expf(v[i] - m);
#pragma unroll
  for (int off = 32; off > 0; off >>= 1) s += __shfl_down(s, off);
  if ((t & 63) == 0) sm[t >> 6] = s;
  __syncthreads();
  const float lse = m + logf(sm[0] + sm[1] + sm[2] + sm[3]);
#pragma unroll
  for (int i = 0; i < 32; ++i) p[t + 256 * i] = v[i] - lse;
}

// ---------------- host orchestration ----------------
extern "C" void kernel_launch(void* const* d_in, const int* in_sizes, int n_in,
                              void* d_out, int out_size, void* d_ws, size_t ws_size,
                              hipStream_t stream) {
  if (ws_size < WS_FLOATS * sizeof(float)) return;

  const int*   x        = (const int*)d_in[0];
  const float* cache    = (const float*)d_in[1];
  const float* emb      = (const float*)d_in[2];
  const float* out_bias = (const float*)d_in[3];
  const float* Wqw      = (const float*)d_in[4];
  const float* Wkw      = (const float*)d_in[5];
  const float* Wvw      = (const float*)d_in[6];
  const float* Wow      = (const float*)d_in[7];
  const float* w_dc     = (const float*)d_in[8];
  const float* b_dc     = (const float*)d_in[9];
  const float* Wr       = (const float*)d_in[10];
  const float* Wrc      = (const float*)d_in[11];
  const float* brc      = (const float*)d_in[12];
  const float* rw       = (const float*)d_in[13];
  const float* rr       = (const float*)d_in[14];
  const float* g1       = (const float*)d_in[15];
  const float* b1       = (const float*)d_in[16];
  const float* g2       = (const float*)d_in[17];
  const float* b2       = (const float*)d_in[18];
  const float* gd       = (const float*)d_in[19];
  const float* bd       = (const float*)d_in[20];
  const float* gw       = (const float*)d_in[21];
  const float* bw       = (const float*)d_in[22];
  const float* wf1      = (const float*)d_in[23];
  const float* bf1      = (const float*)d_in[24];
  const float* wf2      = (const float*)d_in[25];
  const float* bf2      = (const float*)d_in[26];

  float* ws   = (float*)d_ws;
  float* hbuf = ws + F_H;
  float* attb = ws + F_ATT;
  float* abuf = ws + F_ATT;          // alias: attb is dead once attbf exists
  float* qb   = ws + F_Q;
  float* hwb  = ws + F_HW;
  float* kwb  = ws + F_KW;
  float* vwb  = ws + F_VW;
  float* comp = ws + F_COMP;
  float* kcb  = ws + F_KC;
  float* vcb  = ws + F_VC;
  float* scc  = ws + F_SCC;
  float* sch  = ws + F_SCH;
  float* pwin = ws + F_PWIN;
  float* kpe  = ws + F_KPE;
  float* Pwb  = ws + F_PWB;
  float* Pcb  = ws + F_PCB;
  unsigned short* bfb    = (unsigned short*)(ws + F_BF);
  unsigned short* WqT    = bfb + U_WQT;
  unsigned short* WkT    = bfb + U_WKT;
  unsigned short* WvT    = bfb + U_WVT;
  unsigned short* WoT    = bfb + U_WOT;
  unsigned short* WrT    = bfb + U_WRT;
  unsigned short* WF1T   = bfb + U_WF1T;
  unsigned short* WF2T   = bfb + U_WF2T;
  unsigned short* hbf    = bfb + U_HBF;
  unsigned short* hwbf   = bfb + U_HWBF;
  unsigned short* attbf  = bfb + U_HWBF;   // alias (hwbf dead by then)
  unsigned short* ffbf   = bfb + U_FFBF;
  unsigned short* embbf  = bfb + U_FFBF;   // alias (ffbf dead after last layer)
  unsigned short* compbf = bfb + U_COMPBF;
  unsigned short* pwinbf = bfb + U_PWINBF;
  float* outp = (float*)d_out;

  embed_kernel<<<(Bq * Lq * Dq) / 256, 256, 0, stream>>>(x, emb, hbuf);
  posemb_kernel<<<((Wwin + NCVq) * Dq) / 256, 256, 0, stream>>>(pwin, kpe);
  cvt_bf16_kernel<<<(Wwin * Dq) / 1024, 256, 0, stream>>>(pwin, pwinbf);

  for (int l = 0; l < NLq; ++l) {
    const float* cache_l = cache + (size_t)l * Bq * Mq * Dq;
    const float* Wq_l  = Wqw + (size_t)l * Dq * Dq;
    const float* Wk_l  = Wkw + (size_t)l * Dq * Dq;
    const float* Wv_l  = Wvw + (size_t)l * Dq * Dq;
    const float* Wo_l  = Wow + (size_t)l * Dq * Dq;
    const float* wdc_l = w_dc + (size_t)l * Dq * 16;
    const float* bdc_l = b_dc + (size_t)l * 16;
    const float* Wr_l  = Wr  + (size_t)l * Dq * Dq;
    const float* Wrc_l = Wrc + (size_t)l * Dq * Dq;
    const float* brc_l = brc + (size_t)l * Dq;
    const float* rw_l  = rw  + (size_t)l * Hq * 64;
    const float* rr_l  = rr  + (size_t)l * Hq * 64;
    const float* g1_l  = g1 + (size_t)l * Dq;  const float* b1_l = b1 + (size_t)l * Dq;
    const float* g2_l  = g2 + (size_t)l * Dq;  const float* b2_l = b2 + (size_t)l * Dq;
    const float* gd_l  = gd + (size_t)l * Dq;  const float* bd_l = bd + (size_t)l * Dq;
    const float* gw_l  = gw + (size_t)l * Dq;  const float* bw_l = bw + (size_t)l * Dq;
    const float* wf1_l = wf1 + (size_t)l * Dq * DFFq;
    const float* bf1_l = bf1 + (size_t)l * DFFq;
    const float* wf2_l = wf2 + (size_t)l * DFFq * Dq;
    const float* bf2_l = bf2 + (size_t)l * Dq;

    // weight transposes+convert for this layer
    tcvt_kernel<<<dim3(16, 16), 256, 0, stream>>>(Wq_l, WqT, Dq, Dq);
    tcvt_kernel<<<dim3(16, 16), 256, 0, stream>>>(Wk_l, WkT, Dq, Dq);
    tcvt_kernel<<<dim3(16, 16), 256, 0, stream>>>(Wv_l, WvT, Dq, Dq);
    tcvt_kernel<<<dim3(16, 16), 256, 0, stream>>>(Wo_l, WoT, Dq, Dq);
    tcvt_kernel<<<dim3(16, 16), 256, 0, stream>>>(Wr_l, WrT, Dq, Dq);
    tcvt_kernel<<<dim3(64, 16), 256, 0, stream>>>(wf1_l, WF1T, Dq, DFFq);
    tcvt_kernel<<<dim3(16, 64), 256, 0, stream>>>(wf2_l, WF2T, DFFq, Dq);

    // compression scores + compress
    gemm_kernel<0, 1><<<dim3(1, 64), 256, 0, stream>>>(cache_l, wdc_l, bdc_l, scc, Bq * Mq, 16, Dq);
    gemm_kernel<0, 1><<<dim3(1, 64), 256, 0, stream>>>(hbuf, wdc_l, bdc_l, sch, Bq * Lq, 16, Dq);
    compress_kernel<<<Bq * 64 * Hq, 64, 0, stream>>>(scc, sch, cache_l, hbuf, comp);
    cvt_bf16_kernel<<<(Bq * NCVq * Dq) / 1024, 256, 0, stream>>>(comp, compbf);
    // compressed K/V
    gemm_bf16_kernel<0><<<dim3(8, 1), 256, 0, stream>>>(compbf, WkT, nullptr, kcb, Bq * NCVq, Dq, Dq);
    ln_kernel<<<Bq * NCVq, 256, 0, stream>>>(kcb, nullptr, gd_l, bd_l, kcb);
    gemm_bf16_kernel<0><<<dim3(8, 1), 256, 0, stream>>>(compbf, WvT, nullptr, vcb, Bq * NCVq, Dq, Dq);
    ln_kernel<<<Bq * NCVq, 256, 0, stream>>>(vcb, nullptr, gd_l, bd_l, vcb);
    // window K/V
    hwbuild_kernel<<<(Bq * HWLEN * (Dq / 4)) / 256, 256, 0, stream>>>(cache_l, hbuf, hwb);
    cvt_bf16_kernel<<<(Bq * HWLEN * Dq) / 1024, 256, 0, stream>>>(hwb, hwbf);
    gemm_bf16_kernel<0><<<dim3(8, 40), 256, 0, stream>>>(hwbf, WkT, nullptr, kwb, Bq * HWLEN, Dq, Dq);
    ln_kernel<<<Bq * HWLEN, 256, 0, stream>>>(kwb, nullptr, gw_l, bw_l, kwb);
    gemm_bf16_kernel<0><<<dim3(8, 40), 256, 0, stream>>>(hwbf, WvT, nullptr, vwb, Bq * HWLEN, Dq, Dq);
    ln_kernel<<<Bq * HWLEN, 256, 0, stream>>>(vwb, nullptr, gw_l, bw_l, vwb);
    // Q and positional projections
    cvt_bf16_kernel<<<(Bq * Lq * Dq) / 1024, 256, 0, stream>>>(hbuf, hbf);
    gemm_bf16_kernel<0><<<dim3(8, 32), 256, 0, stream>>>(hbf, WqT, nullptr, qb, Bq * Lq, Dq, Dq);
    gemm_bf16_kernel<0><<<dim3(8, 4), 256, 0, stream>>>(pwinbf, WrT, nullptr, Pwb, Wwin, Dq, Dq);
    gemm_kernel<0, 1><<<dim3(16, 1), 256, 0, stream>>>(kpe, Wrc_l, brc_l, Pcb, NCVq, Dq, Dq);
    // fused attention (fp32)
    attn_kernel<<<Bq * Hq * 64, 1024, 0, stream>>>(qb, kwb, vwb, kcb, vcb, Pwb, Pcb, rw_l, rr_l, attb);
    // O projection + residual LN
    cvt_bf16_kernel<<<(Bq * Lq * Dq) / 1024, 256, 0, stream>>>(attb, attbf);
    gemm_bf16_kernel<0><<<dim3(8, 32), 256, 0, stream>>>(attbf, WoT, nullptr, abuf, Bq * Lq, Dq, Dq);
    ln_kernel<<<Bq * Lq, 256, 0, stream>>>(hbuf, abuf, g1_l, b1_l, hbuf);
    // FFN
    cvt_bf16_kernel<<<(Bq * Lq * Dq) / 1024, 256, 0, stream>>>(hbuf, hbf);
    gemm_bf16_kernel<2><<<dim3(32, 32), 256, 0, stream>>>(hbf, WF1T, bf1_l, ffbf, Bq * Lq, DFFq, Dq);
    gemm_bf16_kernel<1><<<dim3(8, 32), 256, 0, stream>>>(ffbf, WF2T, bf2_l, abuf, Bq * Lq, Dq, DFFq);
    ln_kernel<<<Bq * Lq, 256, 0, stream>>>(hbuf, abuf, g2_l, b2_l, hbuf);
  }

  // LM head + log_softmax
  cvt_bf16_kernel<<<(Bq * Lq * Dq) / 1024, 256, 0, stream>>>(hbuf, hbf);
  cvt_bf16_kernel<<<(Vq * Dq) / 1024, 256, 0, stream>>>(emb, embbf);
  gemm_bf16_kernel<1><<<dim3(Vq / 128, (Bq * Lq) / 128), 256, 0, stream>>>(hbf, embbf, out_bias,
                                                                           outp, Bq * Lq, Vq, Dq);
  logsoftmax_kernel<<<Bq * Lq, 256, 0, stream>>>(outp);
}